// Round 1
// 311.086 us; speedup vs baseline: 1.0099x; 1.0099x over previous
//
#include <hip/hip_runtime.h>

// AtomFeatureEmbedder on MI355X (gfx950).
// R4 theory: plm is 99.6% zeros (uid match rate ~1/256). The previous dense
// kernel streamed 268.4 MB of mostly-zero float4 stores at only ~1.8 TB/s
// effective (inferred ~149 us; the harness fill kernel does 6.5 TB/s on this
// same buffer). New structure:
//   1. hipMemsetAsync zeroes the plm region (268.4 MB -> ~41 us at fill BW).
//      Memset nodes are graph-capture-legal (the harness's own reset uses them).
//   2. Kernel writes ONLY the ~16K matching pairs (~1 MB) + the cl GEMM.
// Predicted: kernel 149 -> ~15 us, total GPU work ~55-60 us + fixed poison.

#define N_ATOMS   2048
#define C_ATOM    128
#define C_PAIR    16
#define CL_ATOMS  8                      // atoms per cl block
#define CL_BLOCKS (N_ATOMS / CL_ATOMS)   // 256
#define KP        392                    // 390 features padded to multiple of 4
#define CL_FLOATS ((size_t)N_ATOMS * C_ATOM)                       // 262144
#define PLM_BYTES ((size_t)N_ATOMS * N_ATOMS * C_PAIR * 4)         // 268435456

extern "C" __global__ __launch_bounds__(256)
void atom_embed_kernel(const float* __restrict__ pos,      // [2048,3] f32
                       const float* __restrict__ mask,     // [2048]
                       const float* __restrict__ elem,     // [2048,128]
                       const float* __restrict__ charge,   // [2048]
                       const float* __restrict__ chars,    // [2048,256]
                       const int*   __restrict__ uid,      // [2048] int32
                       const float* __restrict__ Wf,       // [390,128]
                       const float* __restrict__ Woff,     // [3,16]
                       const float* __restrict__ Winv,     // [1,16]
                       const float* __restrict__ Wmask,    // [1,16]
                       float* __restrict__ out)            // cl (262144) then plm
{
    const int tid = threadIdx.x;

    if (blockIdx.x < CL_BLOCKS) {
        // ---------------- cl = feats @ W_feats (unchanged, verified) --------
        __shared__ __align__(16) float sf[CL_ATOMS * KP];
        const int atom0 = blockIdx.x * CL_ATOMS;

        // Stage 8 atoms x 390 features into LDS; pad [390..391] with 0.
        for (int idx = tid; idx < CL_ATOMS * KP; idx += 256) {
            const int a = idx / KP;
            const int k = idx - a * KP;
            const int ga = atom0 + a;
            float v = 0.0f;
            if (k < 3)          v = pos[ga * 3 + k];
            else if (k == 3)    v = mask[ga];
            else if (k < 132)   v = elem[ga * 128 + (k - 4)];
            else if (k == 132)  v = charge[ga];
            else if (k < 389)   v = chars[ga * 256 + (k - 133)];
            else if (k == 389)  v = (float)uid[ga];
            sf[idx] = v;
        }
        __syncthreads();

        const int col = tid & 127;
        const int sub = tid >> 7;          // 0 or 1 -> atoms [sub*4, sub*4+4)
        const float* sfa = &sf[sub * 4 * KP];
        float acc[4] = {0.f, 0.f, 0.f, 0.f};

        for (int k0 = 0; k0 < 388; k0 += 4) {
            const float w0 = Wf[(k0 + 0) * 128 + col];
            const float w1 = Wf[(k0 + 1) * 128 + col];
            const float w2 = Wf[(k0 + 2) * 128 + col];
            const float w3 = Wf[(k0 + 3) * 128 + col];
            #pragma unroll
            for (int a = 0; a < 4; a++) {
                const float4 f = *(const float4*)&sfa[a * KP + k0];
                acc[a] += f.x * w0 + f.y * w1 + f.z * w2 + f.w * w3;
            }
        }
        {   // tail: k = 388, 389
            const float w0 = Wf[388 * 128 + col];
            const float w1 = Wf[389 * 128 + col];
            #pragma unroll
            for (int a = 0; a < 4; a++) {
                const float2 f = *(const float2*)&sfa[a * KP + 388];
                acc[a] += f.x * w0 + f.y * w1;
            }
        }
        #pragma unroll
        for (int a = 0; a < 4; a++) {
            const int ga = atom0 + sub * 4 + a;
            out[ga * 128 + col] = acc[a];
        }
    } else {
        // ---------------- plm, sparse: only matching pairs ------------------
        // plm region was already zeroed by hipMemsetAsync on this stream.
        const int l  = blockIdx.x - CL_BLOCKS;     // [0, 2048)
        const int ul = uid[l];
        const float lx = pos[l * 3 + 0];
        const float ly = pos[l * 3 + 1];
        const float lz = pos[l * 3 + 2];

        float4* rowp = (float4*)(out + CL_FLOATS + (size_t)l * N_ATOMS * C_PAIR);

        // 8 coalesced uid loads per thread (8 KB array, L1-resident),
        // issued together so one waitcnt covers all of them.
        int u[8];
        #pragma unroll
        for (int i = 0; i < 8; i++) u[i] = uid[i * 256 + tid];

        #pragma unroll
        for (int i = 0; i < 8; i++) {
            if (u[i] == ul) {              // ~0.4% of lanes taken
                const int m = i * 256 + tid;
                const float dx = pos[m * 3 + 0] - lx;
                const float dy = pos[m * 3 + 1] - ly;
                const float dz = pos[m * 3 + 2] - lz;
                const float invd = 1.0f / (1.0f + sqrtf(dx * dx + dy * dy + dz * dz));
                float4* dst = rowp + m * 4;    // 64 B for this pair
                #pragma unroll
                for (int g = 0; g < 4; g++) {
                    const float4 wx = *(const float4*)&Woff[4 * g];
                    const float4 wy = *(const float4*)&Woff[16 + 4 * g];
                    const float4 wz = *(const float4*)&Woff[32 + 4 * g];
                    const float4 wi = *(const float4*)&Winv[4 * g];
                    const float4 wm = *(const float4*)&Wmask[4 * g];
                    float4 v;
                    v.x = dx * wx.x + dy * wy.x + dz * wz.x + invd * wi.x + wm.x;
                    v.y = dx * wx.y + dy * wy.y + dz * wz.y + invd * wi.y + wm.y;
                    v.z = dx * wx.z + dy * wy.z + dz * wz.z + invd * wi.z + wm.z;
                    v.w = dx * wx.w + dy * wy.w + dz * wz.w + invd * wi.w + wm.w;
                    dst[g] = v;
                }
            }
        }
    }
}

extern "C" void kernel_launch(void* const* d_in, const int* in_sizes, int n_in,
                              void* d_out, int out_size, void* d_ws, size_t ws_size,
                              hipStream_t stream) {
    const float* pos    = (const float*)d_in[0];
    const float* rmask  = (const float*)d_in[1];
    const float* elem   = (const float*)d_in[2];
    const float* charge = (const float*)d_in[3];
    const float* chars  = (const float*)d_in[4];
    const int*   uid    = (const int*)d_in[5];
    const float* Wf     = (const float*)d_in[6];
    const float* Woff   = (const float*)d_in[7];
    const float* Winv   = (const float*)d_in[8];
    const float* Wmask  = (const float*)d_in[9];
    float* out = (float*)d_out;

    // Zero the plm region at fill-kernel bandwidth (~6.5 TB/s demonstrated on
    // this buffer); stream-ordered, so the kernel's sparse writes land after.
    hipMemsetAsync((char*)out + CL_FLOATS * sizeof(float), 0, PLM_BYTES, stream);

    dim3 grid(CL_BLOCKS + N_ATOMS);  // cl blocks first (now the long pole)
    atom_embed_kernel<<<grid, 256, 0, stream>>>(
        pos, rmask, elem, charge, chars, uid, Wf, Woff, Winv, Wmask, out);
}